// Round 7
// baseline (1177.021 us; speedup 1.0000x reference)
//
#include <hip/hip_runtime.h>
#include <math.h>

#define BATCH 2
#define TSEQ 1024
#define DIM 1024
#define NLAYER 12
#define EDIM 4096
#define BT 2048
#define EPS_LN 1e-5f

typedef __attribute__((ext_vector_type(4))) float  f32x4;
typedef __attribute__((ext_vector_type(8))) __bf16 bf16x8;
typedef __attribute__((ext_vector_type(4))) __bf16 bf16x4;

__device__ __forceinline__ void gl_lds16(const void* gptr, void* lptr) {
    __builtin_amdgcn_global_load_lds(
        (const __attribute__((address_space(1))) void*)gptr,
        (__attribute__((address_space(3))) void*)lptr,
        16, 0, 0);
}

// ---- 64x64 f32->bf16 transpose tile, one 256-thread team ------------------
__device__ __forceinline__ void wtile256(float (*t)[65], const float* src,
                                         __bf16* dst, int R, int C,
                                         int rt, int ct, int tid)
{
    int lr = tid >> 2, cs = (tid & 3) << 4;
    const float* sp = src + (size_t)(rt * 64 + lr) * C + ct * 64 + cs;
#pragma unroll
    for (int s = 0; s < 4; s++) {
        f32x4 v = *(const f32x4*)(sp + s * 4);
        t[lr][cs + s * 4 + 0] = v[0];
        t[lr][cs + s * 4 + 1] = v[1];
        t[lr][cs + s * 4 + 2] = v[2];
        t[lr][cs + s * 4 + 3] = v[3];
    }
    __syncthreads();
    int oc = tid >> 2, rs = (tid & 3) << 4;
    bf16x8 o0, o1;
#pragma unroll
    for (int e = 0; e < 8; e++) o0[e] = (__bf16)t[rs + e][oc];
#pragma unroll
    for (int e = 0; e < 8; e++) o1[e] = (__bf16)t[rs + 8 + e][oc];
    __bf16* dp = dst + (size_t)(ct * 64 + oc) * R + rt * 64 + rs;
    *(bf16x8*)dp = o0;
    *(bf16x8*)(dp + 8) = o1;
}

// ----------------------------------------- standalone wtrans (layer 0) ----
__global__ __launch_bounds__(256) void wtrans_kernel(
    const float* __restrict__ W1, const float* __restrict__ W2,
    __bf16* __restrict__ W1t, __bf16* __restrict__ W2t)
{
    __shared__ float t[64][65];
    int z = blockIdx.z;
    if (z == 0) wtile256(t, W1, W1t, DIM, EDIM, blockIdx.y, blockIdx.x, threadIdx.x);
    else        wtile256(t, W2, W2t, EDIM, DIM, blockIdx.x, blockIdx.y, threadIdx.x);
}

// ---------------- fused: attn (blocks 0..2047) + wtrans (2048..4095) -------
// attn: one block per bt row. Wave w owns history rows lp = w, w+4, w+8.
// hist holds slots 1..12 (slot s at hist + (s-1)*BT*DIM); lp==0 reads x.
// If part != NULL, the newest slot (lp == nl-1) is assembled on the fly:
// row = base + sum of 4 bf16 split-K partials, written back to hist.
// Writes hnext = resid + b2 (f32) and u = LN(h) (bf16).
__global__ __launch_bounds__(256)
void attn_wt_kernel(const float* __restrict__ x,
                    const float* __restrict__ hist,
                    const __bf16* __restrict__ part,
                    const float* __restrict__ q,
                    const float* __restrict__ kng,
                    const float* __restrict__ knb,
                    const float* __restrict__ lng,
                    const float* __restrict__ lnb,
                    const float* __restrict__ b2,
                    float* __restrict__ hnext,
                    __bf16* __restrict__ u,
                    int nl,
                    const float* __restrict__ W1n,
                    const float* __restrict__ W2n,
                    __bf16* __restrict__ W1tn,
                    __bf16* __restrict__ W2tn,
                    int dowt)
{
    __shared__ char smem[49408];

    if (blockIdx.x >= BT) {
        if (!dowt) return;
        float (*t)[65] = (float(*)[65])smem;
        int tile = blockIdx.x - BT;
        if (tile < 1024) wtile256(t, W1n, W1tn, DIM, EDIM, tile >> 6, tile & 63, threadIdx.x);
        else { int t3 = tile - 1024; wtile256(t, W2n, W2tn, EDIM, DIM, t3 & 63, t3 >> 6, threadIdx.x); }
        return;
    }

    float (*V)[DIM] = (float(*)[DIM])smem;                    // [12][1024]
    float* sS  = (float*)(smem + 49152);
    float* sMu = sS + NLAYER;
    float* sRs = sMu + NLAYER;

    const int bt = blockIdx.x;
    const int tid = threadIdx.x, lane = tid & 63, w = tid >> 6;

    f32x4 gqv[4];
    float sg = 0.f, sb = 0.f;
#pragma unroll
    for (int i = 0; i < 4; i++) {
        int d = i * 256 + lane * 4;
        f32x4 g4 = *(const f32x4*)(kng + d);
        f32x4 q4 = *(const f32x4*)(q + d);
        f32x4 b4 = *(const f32x4*)(knb + d);
#pragma unroll
        for (int c = 0; c < 4; c++) {
            float gq = g4[c] * q4[c];
            gqv[i][c] = gq;
            sg += gq;
            sb += b4[c] * q4[c];
        }
    }
#pragma unroll
    for (int off = 32; off; off >>= 1) {
        sg += __shfl_xor(sg, off);
        sb += __shfl_xor(sb, off);
    }

    for (int lp = w; lp < nl; lp += 4) {
        const float* vp = (lp == 0) ? (x + (size_t)bt * DIM)
                                    : (hist + ((size_t)(lp - 1) * BT + bt) * DIM);
        f32x4 vv[4];
#pragma unroll
        for (int i = 0; i < 4; i++) vv[i] = *(const f32x4*)(vp + i * 256 + lane * 4);

        if (part && lp == nl - 1) {
            // assemble newest slot: base + 4 split-K partials, write back
#pragma unroll
            for (int z = 0; z < 4; z++) {
                const __bf16* pp = part + ((size_t)z * BT + bt) * DIM;
#pragma unroll
                for (int i = 0; i < 4; i++) {
                    bf16x4 p4 = *(const bf16x4*)(pp + i * 256 + lane * 4);
#pragma unroll
                    for (int c = 0; c < 4; c++) vv[i][c] += (float)p4[c];
                }
            }
            float* wb = const_cast<float*>(vp);
#pragma unroll
            for (int i = 0; i < 4; i++) *(f32x4*)(wb + i * 256 + lane * 4) = vv[i];
        }

        float s1 = 0.f, s2 = 0.f, sq = 0.f;
#pragma unroll
        for (int i = 0; i < 4; i++) {
            *(f32x4*)(&V[lp][i * 256 + lane * 4]) = vv[i];
#pragma unroll
            for (int c = 0; c < 4; c++) {
                float xv = vv[i][c];
                s1 += xv; s2 += xv * xv; sq += xv * gqv[i][c];
            }
        }
#pragma unroll
        for (int off = 32; off; off >>= 1) {
            s1 += __shfl_xor(s1, off);
            s2 += __shfl_xor(s2, off);
            sq += __shfl_xor(sq, off);
        }
        if (lane == 0) {
            float mu = s1 * (1.0f / DIM);
            float var = s2 * (1.0f / DIM) - mu * mu;
            float rs = rsqrtf(var + EPS_LN);
            sMu[lp] = mu; sRs[lp] = rs;
            sS[lp] = (rs * (sq - mu * sg) + sb) * (1.0f / 32.0f);
        }
    }
    __syncthreads();

    float mx = -1e30f;
#pragma unroll
    for (int i = 0; i < NLAYER; i++) if (i < nl) mx = fmaxf(mx, sS[i]);
    float al[NLAYER];
    float ssum = 0.f;
#pragma unroll
    for (int i = 0; i < NLAYER; i++) {
        al[i] = (i < nl) ? __expf(sS[i] - mx) : 0.f;
        ssum += al[i];
    }
    float inv = 1.0f / ssum;

    const int d = tid * 4;
    f32x4 r; r[0] = 0.f; r[1] = 0.f; r[2] = 0.f; r[3] = 0.f;
#pragma unroll
    for (int i = 0; i < NLAYER; i++) {
        if (i < nl) {
            f32x4 v4 = *(const f32x4*)(&V[i][d]);
            float a = al[i] * inv;
            r[0] += a * v4[0]; r[1] += a * v4[1]; r[2] += a * v4[2]; r[3] += a * v4[3];
        }
    }
    f32x4 h4 = *(const f32x4*)(&V[nl - 1][d]);
    f32x4 b24 = *(const f32x4*)(b2 + d);
    f32x4 ro; ro[0] = r[0] + b24[0]; ro[1] = r[1] + b24[1];
    ro[2] = r[2] + b24[2]; ro[3] = r[3] + b24[3];
    *(f32x4*)(hnext + (size_t)bt * DIM + d) = ro;

    float mu = sMu[nl - 1], rs = sRs[nl - 1];
    f32x4 g4 = *(const f32x4*)(lng + d);
    f32x4 b4 = *(const f32x4*)(lnb + d);
    bf16x4 uo;
#pragma unroll
    for (int c = 0; c < 4; c++) uo[c] = (__bf16)((h4[c] - mu) * rs * g4[c] + b4[c]);
    *(bf16x4*)(u + (size_t)bt * DIM + d) = uo;
}

// ------------------------------------------------------------------ GEMM ---
// C = A(bf16 MxK) * Bt(bf16 NxK)^T.  256x256 tile, 8 waves (128x64 each),
// BK=64, K=1024 per block (16 steps). 2-buffer, ONE barrier per step:
//   vmcnt(0) [tile t landed; hidden under compute(t-1)] -> s_barrier
//   -> STAGE(t+1) into buf (t+1)&1 [its readers just passed the barrier]
//   -> ds_read + MFMA on buf t&1.
// Pre-swizzled global source => conflict-free ds_read_b128; setprio on MFMA.
// EPI==0: bf16 gelu(acc+bias) -> hmid. EPI==2: bf16 split-K partial slice.
template <int EPI, int NTN>
__global__ __launch_bounds__(512, 1)
void gemm256v2(const __bf16* __restrict__ A, const __bf16* __restrict__ Bt,
               const float* __restrict__ bias, void* __restrict__ outp,
               int N, int As, int Bs)
{
    __shared__ char lds[131072];           // 2 x (A 32KB + B 32KB)
    const int tid = threadIdx.x, lane = tid & 63, w = tid >> 6;
    const int wm = w >> 2, wn = w & 3;     // 2M x 4N wave grid
    const int lr = lane & 15;
    const int hib = (lane >> 4) << 4;

    const int nb = gridDim.x;              // 128 or 32 (%8==0 -> bijective)
    const int fid = blockIdx.x;
    const int swz = (fid & 7) * (nb >> 3) + (fid >> 3);
    const int m0 = (swz / NTN) * 256;
    const int n0 = (swz % NTN) * 256;
    const int kbase = blockIdx.y * 1024;

    f32x4 acc[8][4];
#pragma unroll
    for (int i = 0; i < 8; i++)
#pragma unroll
        for (int j = 0; j < 4; j++) { acc[i][j][0]=0.f; acc[i][j][1]=0.f; acc[i][j][2]=0.f; acc[i][j][3]=0.f; }

    const int srow = tid >> 3;             // 0..63
    const int ksrc = ((tid & 7) << 4) ^ ((srow & 7) << 4);
    const char* Ac = (const char*)A;
    const char* Bc = (const char*)Bt;
    size_t aoff[4], boff[4];
#pragma unroll
    for (int c = 0; c < 4; c++) {
        aoff[c] = ((size_t)(m0 + c * 64 + srow) * As + kbase) * 2 + ksrc;
        boff[c] = ((size_t)(n0 + c * 64 + srow) * Bs + kbase) * 2 + ksrc;
    }
    char* abw = lds + w * 1024;
    char* bbw = lds + 32768 + w * 1024;

    auto STAGE = [&](int tt, int p) {
        size_t kb = (size_t)tt * 128;
        char* ab = abw + p * 65536;
        char* bb = bbw + p * 65536;
#pragma unroll
        for (int c = 0; c < 4; c++) gl_lds16(Ac + aoff[c] + kb, ab + c * 8192);
#pragma unroll
        for (int c = 0; c < 4; c++) gl_lds16(Bc + boff[c] + kb, bb + c * 8192);
    };

    STAGE(0, 0);

#pragma unroll 1
    for (int t = 0; t < 16; ++t) {
        asm volatile("s_waitcnt vmcnt(0)" ::: "memory");   // tile t landed
        __builtin_amdgcn_s_barrier();                      // + everyone done reading buf (t+1)&1
        __builtin_amdgcn_sched_barrier(0);
        if (t + 1 < 16) STAGE(t + 1, (t + 1) & 1);

        const char* baseA = lds + (size_t)(t & 1) * 65536;
        const char* baseB = baseA + 32768;
#pragma unroll
        for (int kk = 0; kk < 2; kk++) {
            const int kb = kk * 64 + hib;
            bf16x8 bfr[4];
#pragma unroll
            for (int j = 0; j < 4; j++) {
                int rb = wn * 64 + j * 16 + lr;
                bfr[j] = *(const bf16x8*)(baseB + rb * 128 + (kb ^ ((rb & 7) << 4)));
            }
            bf16x8 afr[4];
#pragma unroll
            for (int i2 = 0; i2 < 4; i2++) {
                int ra = wm * 128 + i2 * 16 + lr;
                afr[i2] = *(const bf16x8*)(baseA + ra * 128 + (kb ^ ((ra & 7) << 4)));
            }
            __builtin_amdgcn_s_setprio(1);
#pragma unroll
            for (int i2 = 0; i2 < 4; i2++)
#pragma unroll
                for (int j = 0; j < 4; j++)
                    acc[i2][j] = __builtin_amdgcn_mfma_f32_16x16x32_bf16(afr[i2], bfr[j], acc[i2][j], 0, 0, 0);
            __builtin_amdgcn_s_setprio(0);
#pragma unroll
            for (int i2 = 0; i2 < 4; i2++) {
                int ra = wm * 128 + (i2 + 4) * 16 + lr;
                afr[i2] = *(const bf16x8*)(baseA + ra * 128 + (kb ^ ((ra & 7) << 4)));
            }
            __builtin_amdgcn_s_setprio(1);
#pragma unroll
            for (int i2 = 0; i2 < 4; i2++)
#pragma unroll
                for (int j = 0; j < 4; j++)
                    acc[i2 + 4][j] = __builtin_amdgcn_mfma_f32_16x16x32_bf16(afr[i2], bfr[j], acc[i2 + 4][j], 0, 0, 0);
            __builtin_amdgcn_s_setprio(0);
        }
    }

    const int lrow = (lane >> 4) << 2;
    if (EPI == 0) {
        __bf16* out = (__bf16*)outp;
#pragma unroll
        for (int i = 0; i < 8; i++) {
#pragma unroll
            for (int j = 0; j < 4; j++) {
                int colg = n0 + wn * 64 + j * 16 + lr;
                float bc = bias[colg];
#pragma unroll
                for (int r = 0; r < 4; r++) {
                    int rowg = m0 + wm * 128 + i * 16 + lrow + r;
                    float v = acc[i][j][r] + bc;
                    float tt2 = 0.7978845608f * (v + 0.044715f * v * v * v);
                    float e = __expf(2.0f * tt2);
                    float th = 1.0f - 2.0f / (e + 1.0f);
                    out[(size_t)rowg * N + colg] = (__bf16)(0.5f * v * (1.0f + th));
                }
            }
        }
    } else {
        __bf16* out = (__bf16*)outp + (size_t)blockIdx.y * BT * N;
#pragma unroll
        for (int i = 0; i < 8; i++) {
#pragma unroll
            for (int j = 0; j < 4; j++) {
                int colg = n0 + wn * 64 + j * 16 + lr;
#pragma unroll
                for (int r = 0; r < 4; r++) {
                    int rowg = m0 + wm * 128 + i * 16 + lrow + r;
                    out[(size_t)rowg * N + colg] = (__bf16)acc[i][j][r];
                }
            }
        }
    }
}

// ------------------------------------- final assembly (layer 12) -> d_out --
__global__ void final_reduce(const float* __restrict__ base,
                             const __bf16* __restrict__ part,
                             float* __restrict__ out)
{
    size_t i = ((size_t)blockIdx.x * 256 + threadIdx.x) * 4;
    f32x4 r = *(const f32x4*)(base + i);
#pragma unroll
    for (int z = 0; z < 4; z++) {
        bf16x4 p = *(const bf16x4*)(part + (size_t)z * BT * DIM + i);
#pragma unroll
        for (int c = 0; c < 4; c++) r[c] += (float)p[c];
    }
    *(f32x4*)(out + i) = r;
}

// ---------------------------------------------------------------- launch ---
extern "C" void kernel_launch(void* const* d_in, const int* in_sizes, int n_in,
                              void* d_out, int out_size, void* d_ws, size_t ws_size,
                              hipStream_t stream)
{
    const float* x   = (const float*)d_in[0];
    const float* q   = (const float*)d_in[1];
    const float* kng = (const float*)d_in[2];
    const float* knb = (const float*)d_in[3];
    const float* lng = (const float*)d_in[4];
    const float* lnb = (const float*)d_in[5];
    const float* W1  = (const float*)d_in[6];
    const float* b1  = (const float*)d_in[7];
    const float* W2  = (const float*)d_in[8];
    const float* b2  = (const float*)d_in[9];

    char* ws = (char*)d_ws;
    const size_t slot = (size_t)BT * DIM;            // 2M elements = 8 MB f32
    float*  hist  = (float*)(ws);                    // slots 1..12: 96 MB
    __bf16* ubuf  = (__bf16*)(ws + 100663296);       // 4 MB
    __bf16* hmid  = (__bf16*)(ws + 104857600);       // 16 MB
    __bf16* W1tb[2] = { (__bf16*)(ws + 121634816), (__bf16*)(ws + 130023424) };
    __bf16* W2tb[2] = { (__bf16*)(ws + 138412032), (__bf16*)(ws + 146800640) };
    __bf16* part  = (__bf16*)(ws + 155189248);       // 16 MB (end ~172 MB)

    wtrans_kernel<<<dim3(64, 16, 2), 256, 0, stream>>>(W1, W2, W1tb[0], W2tb[0]);

    for (int l = 0; l < NLAYER; l++) {
        int nl = l + 1;
        int ln = (l + 1 < NLAYER) ? l + 1 : l;
        float* hnext = hist + (size_t)l * slot;      // slot l+1
        attn_wt_kernel<<<dim3(2 * BT), 256, 0, stream>>>(
            x, hist, (l >= 1) ? part : (const __bf16*)nullptr,
            q + (size_t)l * DIM,
            kng + (size_t)l * DIM, knb + (size_t)l * DIM,
            lng + (size_t)l * DIM, lnb + (size_t)l * DIM,
            b2 + (size_t)l * DIM, hnext, ubuf, nl,
            W1 + (size_t)ln * DIM * EDIM, W2 + (size_t)ln * EDIM * DIM,
            W1tb[(l + 1) & 1], W2tb[(l + 1) & 1], (l + 1 < NLAYER) ? 1 : 0);
        gemm256v2<0, 16><<<dim3(128, 1), 512, 0, stream>>>(
            ubuf, W1tb[l & 1], b1 + (size_t)l * EDIM, (void*)hmid, EDIM, DIM, DIM);
        gemm256v2<2, 4><<<dim3(32, 4), 512, 0, stream>>>(
            hmid, W2tb[l & 1], nullptr, (void*)part, DIM, EDIM, EDIM);
    }

    final_reduce<<<dim3(BT * DIM / 1024), 256, 0, stream>>>(
        hist + (size_t)(NLAYER - 1) * slot, part, (float*)d_out);
}

// Round 8
// 916.206 us; speedup vs baseline: 1.2847x; 1.2847x over previous
//
#include <hip/hip_runtime.h>
#include <math.h>

#define BATCH 2
#define TSEQ 1024
#define DIM 1024
#define NLAYER 12
#define EDIM 4096
#define BT 2048
#define EPS_LN 1e-5f

typedef __attribute__((ext_vector_type(4))) float  f32x4;
typedef __attribute__((ext_vector_type(8))) __bf16 bf16x8;
typedef __attribute__((ext_vector_type(4))) __bf16 bf16x4;

__device__ __forceinline__ void gl_lds16(const void* gptr, void* lptr) {
    __builtin_amdgcn_global_load_lds(
        (const __attribute__((address_space(1))) void*)gptr,
        (__attribute__((address_space(3))) void*)lptr,
        16, 0, 0);
}

// ---- 64x64 f32->bf16 transpose tile, one 256-thread team ------------------
__device__ __forceinline__ void wtile256(float (*t)[65], const float* src,
                                         __bf16* dst, int R, int C,
                                         int rt, int ct, int tid)
{
    int lr = tid >> 2, cs = (tid & 3) << 4;
    const float* sp = src + (size_t)(rt * 64 + lr) * C + ct * 64 + cs;
#pragma unroll
    for (int s = 0; s < 4; s++) {
        f32x4 v = *(const f32x4*)(sp + s * 4);
        t[lr][cs + s * 4 + 0] = v[0];
        t[lr][cs + s * 4 + 1] = v[1];
        t[lr][cs + s * 4 + 2] = v[2];
        t[lr][cs + s * 4 + 3] = v[3];
    }
    __syncthreads();
    int oc = tid >> 2, rs = (tid & 3) << 4;
    bf16x8 o0, o1;
#pragma unroll
    for (int e = 0; e < 8; e++) o0[e] = (__bf16)t[rs + e][oc];
#pragma unroll
    for (int e = 0; e < 8; e++) o1[e] = (__bf16)t[rs + 8 + e][oc];
    __bf16* dp = dst + (size_t)(ct * 64 + oc) * R + rt * 64 + rs;
    *(bf16x8*)dp = o0;
    *(bf16x8*)(dp + 8) = o1;
}

// ----------------------------------------- standalone wtrans (layer 0) ----
__global__ __launch_bounds__(256) void wtrans_kernel(
    const float* __restrict__ W1, const float* __restrict__ W2,
    __bf16* __restrict__ W1t, __bf16* __restrict__ W2t)
{
    __shared__ float t[64][65];
    int z = blockIdx.z;
    if (z == 0) wtile256(t, W1, W1t, DIM, EDIM, blockIdx.y, blockIdx.x, threadIdx.x);
    else        wtile256(t, W2, W2t, EDIM, DIM, blockIdx.x, blockIdx.y, threadIdx.x);
}

// ---------------- fused: attn (blocks 0..2047) + wtrans (2048..4095) -------
// attn: one block per bt row. Wave w owns history rows lp = w, w+4, w+8.
// hist holds slots 1..12 (slot s at hist + (s-1)*BT*DIM); lp==0 reads x.
// If part != NULL, the newest slot (lp == nl-1) is assembled on the fly:
// row = base + sum of 4 bf16 split-K partials, written back to hist.
// Writes hnext = resid + b2 (f32) and u = LN(h) (bf16).
__global__ __launch_bounds__(256)
void attn_wt_kernel(const float* __restrict__ x,
                    const float* __restrict__ hist,
                    const __bf16* __restrict__ part,
                    const float* __restrict__ q,
                    const float* __restrict__ kng,
                    const float* __restrict__ knb,
                    const float* __restrict__ lng,
                    const float* __restrict__ lnb,
                    const float* __restrict__ b2,
                    float* __restrict__ hnext,
                    __bf16* __restrict__ u,
                    int nl,
                    const float* __restrict__ W1n,
                    const float* __restrict__ W2n,
                    __bf16* __restrict__ W1tn,
                    __bf16* __restrict__ W2tn,
                    int dowt)
{
    __shared__ char smem[49408];

    if (blockIdx.x >= BT) {
        if (!dowt) return;
        float (*t)[65] = (float(*)[65])smem;
        int tile = blockIdx.x - BT;
        if (tile < 1024) wtile256(t, W1n, W1tn, DIM, EDIM, tile >> 6, tile & 63, threadIdx.x);
        else { int t3 = tile - 1024; wtile256(t, W2n, W2tn, EDIM, DIM, t3 & 63, t3 >> 6, threadIdx.x); }
        return;
    }

    float (*V)[DIM] = (float(*)[DIM])smem;                    // [12][1024]
    float* sS  = (float*)(smem + 49152);
    float* sMu = sS + NLAYER;
    float* sRs = sMu + NLAYER;

    const int bt = blockIdx.x;
    const int tid = threadIdx.x, lane = tid & 63, w = tid >> 6;

    f32x4 gqv[4];
    float sg = 0.f, sb = 0.f;
#pragma unroll
    for (int i = 0; i < 4; i++) {
        int d = i * 256 + lane * 4;
        f32x4 g4 = *(const f32x4*)(kng + d);
        f32x4 q4 = *(const f32x4*)(q + d);
        f32x4 b4 = *(const f32x4*)(knb + d);
#pragma unroll
        for (int c = 0; c < 4; c++) {
            float gq = g4[c] * q4[c];
            gqv[i][c] = gq;
            sg += gq;
            sb += b4[c] * q4[c];
        }
    }
#pragma unroll
    for (int off = 32; off; off >>= 1) {
        sg += __shfl_xor(sg, off);
        sb += __shfl_xor(sb, off);
    }

    for (int lp = w; lp < nl; lp += 4) {
        const float* vp = (lp == 0) ? (x + (size_t)bt * DIM)
                                    : (hist + ((size_t)(lp - 1) * BT + bt) * DIM);
        f32x4 vv[4];
#pragma unroll
        for (int i = 0; i < 4; i++) vv[i] = *(const f32x4*)(vp + i * 256 + lane * 4);

        if (part && lp == nl - 1) {
            // assemble newest slot: base + 4 split-K partials, write back
#pragma unroll
            for (int z = 0; z < 4; z++) {
                const __bf16* pp = part + ((size_t)z * BT + bt) * DIM;
#pragma unroll
                for (int i = 0; i < 4; i++) {
                    bf16x4 p4 = *(const bf16x4*)(pp + i * 256 + lane * 4);
#pragma unroll
                    for (int c = 0; c < 4; c++) vv[i][c] += (float)p4[c];
                }
            }
            float* wb = const_cast<float*>(vp);
#pragma unroll
            for (int i = 0; i < 4; i++) *(f32x4*)(wb + i * 256 + lane * 4) = vv[i];
        }

        float s1 = 0.f, s2 = 0.f, sq = 0.f;
#pragma unroll
        for (int i = 0; i < 4; i++) {
            *(f32x4*)(&V[lp][i * 256 + lane * 4]) = vv[i];
#pragma unroll
            for (int c = 0; c < 4; c++) {
                float xv = vv[i][c];
                s1 += xv; s2 += xv * xv; sq += xv * gqv[i][c];
            }
        }
#pragma unroll
        for (int off = 32; off; off >>= 1) {
            s1 += __shfl_xor(s1, off);
            s2 += __shfl_xor(s2, off);
            sq += __shfl_xor(sq, off);
        }
        if (lane == 0) {
            float mu = s1 * (1.0f / DIM);
            float var = s2 * (1.0f / DIM) - mu * mu;
            float rs = rsqrtf(var + EPS_LN);
            sMu[lp] = mu; sRs[lp] = rs;
            sS[lp] = (rs * (sq - mu * sg) + sb) * (1.0f / 32.0f);
        }
    }
    __syncthreads();

    float mx = -1e30f;
#pragma unroll
    for (int i = 0; i < NLAYER; i++) if (i < nl) mx = fmaxf(mx, sS[i]);
    float al[NLAYER];
    float ssum = 0.f;
#pragma unroll
    for (int i = 0; i < NLAYER; i++) {
        al[i] = (i < nl) ? __expf(sS[i] - mx) : 0.f;
        ssum += al[i];
    }
    float inv = 1.0f / ssum;

    const int d = tid * 4;
    f32x4 r; r[0] = 0.f; r[1] = 0.f; r[2] = 0.f; r[3] = 0.f;
#pragma unroll
    for (int i = 0; i < NLAYER; i++) {
        if (i < nl) {
            f32x4 v4 = *(const f32x4*)(&V[i][d]);
            float a = al[i] * inv;
            r[0] += a * v4[0]; r[1] += a * v4[1]; r[2] += a * v4[2]; r[3] += a * v4[3];
        }
    }
    f32x4 h4 = *(const f32x4*)(&V[nl - 1][d]);
    f32x4 b24 = *(const f32x4*)(b2 + d);
    f32x4 ro; ro[0] = r[0] + b24[0]; ro[1] = r[1] + b24[1];
    ro[2] = r[2] + b24[2]; ro[3] = r[3] + b24[3];
    *(f32x4*)(hnext + (size_t)bt * DIM + d) = ro;

    float mu = sMu[nl - 1], rs = sRs[nl - 1];
    f32x4 g4 = *(const f32x4*)(lng + d);
    f32x4 b4 = *(const f32x4*)(lnb + d);
    bf16x4 uo;
#pragma unroll
    for (int c = 0; c < 4; c++) uo[c] = (__bf16)((h4[c] - mu) * rs * g4[c] + b4[c]);
    *(bf16x4*)(u + (size_t)bt * DIM + d) = uo;
}

// ------------------------------------------------------------------ GEMM ---
// C = A(bf16 MxK) * Bt(bf16 NxK)^T.  128x256 tile, 8 waves (64x64 each),
// BK=64, triple-buffered LDS, prefetch depth 2, counted vmcnt(6), setprio.
// K per block fixed at 1024 (16 K-steps). Column-major tile decomposition
// under the XCD swizzle: same-XCD blocks share a 256-col B panel (L2-resident)
// and iterate the 16 m-tiles (A panel L2-resident per XCD).
// EPI==0: bf16 gelu(acc+bias) -> hmid. EPI==2: bf16 split-K partial slice.
#define STG 49152   // A 16KB + B 32KB per stage

template <int EPI>
__global__ __launch_bounds__(512, 1)
void gemm8(const __bf16* __restrict__ A, const __bf16* __restrict__ Bt,
           const float* __restrict__ bias, void* __restrict__ outp,
           int N, int As, int Bs)
{
    __shared__ char lds[3 * STG];          // 144 KB
    const int tid = threadIdx.x, lane = tid & 63, w = tid >> 6;
    const int wm = w >> 2, wn = w & 3;
    const int lr = lane & 15;
    const int hib = (lane >> 4) << 4;
    const int NT = 16;

    const int nb = gridDim.x;              // 256 or 64 (%8==0 -> bijective)
    const int fid = blockIdx.x;
    const int swz = (fid & 7) * (nb >> 3) + (fid >> 3);
    const int m0 = (swz & 15) * 128;       // col-major: m fast, n slow
    const int n0 = (swz >> 4) * 256;
    const int kbase = blockIdx.y * 1024;

    f32x4 acc[4][4];
#pragma unroll
    for (int i = 0; i < 4; i++)
#pragma unroll
        for (int j = 0; j < 4; j++) { acc[i][j][0]=0.f; acc[i][j][1]=0.f; acc[i][j][2]=0.f; acc[i][j][3]=0.f; }

    const int srow = tid >> 3;
    const int ksrc = ((tid & 7) << 4) ^ ((srow & 7) << 4);
    const char* Ac = (const char*)A;
    const char* Bc = (const char*)Bt;
    size_t aoff[2], boff[4];
#pragma unroll
    for (int c = 0; c < 2; c++)
        aoff[c] = ((size_t)(m0 + c * 64 + srow) * As + kbase) * 2 + ksrc;
#pragma unroll
    for (int c = 0; c < 4; c++)
        boff[c] = ((size_t)(n0 + c * 64 + srow) * Bs + kbase) * 2 + ksrc;

    char* abw = lds + w * 1024;
    char* bbw = lds + 16384 + w * 1024;

    auto STAGE = [&](int tt, int bi) {
        size_t kb = (size_t)tt * 128;
        char* ab = abw + bi * STG;
        char* bb = bbw + bi * STG;
#pragma unroll
        for (int c = 0; c < 2; c++) gl_lds16(Ac + aoff[c] + kb, ab + c * 8192);
#pragma unroll
        for (int c = 0; c < 4; c++) gl_lds16(Bc + boff[c] + kb, bb + c * 8192);
    };

    STAGE(0, 0);
    STAGE(1, 1);

    int sb = 0, st = 2;
#pragma unroll 1
    for (int t = 0; t < NT; ++t) {
        if (t < NT - 1) asm volatile("s_waitcnt vmcnt(6)" ::: "memory");
        else            asm volatile("s_waitcnt vmcnt(0)" ::: "memory");
        __builtin_amdgcn_s_barrier();
        __builtin_amdgcn_sched_barrier(0);

        if (t + 2 < NT) STAGE(t + 2, st);

        const char* base = lds + sb * STG;
        bf16x8 af[2][4], bfr[2][4];
#pragma unroll
        for (int kk = 0; kk < 2; kk++) {
#pragma unroll
            for (int i = 0; i < 4; i++) {
                int ra = wm * 64 + i * 16 + lr;
                af[kk][i] = *(const bf16x8*)(base + ra * 128 + ((kk * 64 + hib) ^ ((ra & 7) << 4)));
            }
#pragma unroll
            for (int j = 0; j < 4; j++) {
                int rb = wn * 64 + j * 16 + lr;
                bfr[kk][j] = *(const bf16x8*)(base + 16384 + rb * 128 + ((kk * 64 + hib) ^ ((rb & 7) << 4)));
            }
        }
        __builtin_amdgcn_s_setprio(1);
#pragma unroll
        for (int kk = 0; kk < 2; kk++)
#pragma unroll
            for (int i = 0; i < 4; i++)
#pragma unroll
                for (int j = 0; j < 4; j++)
                    acc[i][j] = __builtin_amdgcn_mfma_f32_16x16x32_bf16(af[kk][i], bfr[kk][j], acc[i][j], 0, 0, 0);
        __builtin_amdgcn_s_setprio(0);

        sb = (sb == 2) ? 0 : sb + 1;
        st = (st == 2) ? 0 : st + 1;
    }

    const int lrow = (lane >> 4) << 2;
    if (EPI == 0) {
        __bf16* out = (__bf16*)outp;
#pragma unroll
        for (int i = 0; i < 4; i++) {
#pragma unroll
            for (int j = 0; j < 4; j++) {
                int colg = n0 + wn * 64 + j * 16 + lr;
                float bc = bias[colg];
#pragma unroll
                for (int r = 0; r < 4; r++) {
                    int rowg = m0 + wm * 64 + i * 16 + lrow + r;
                    float v = acc[i][j][r] + bc;
                    float tt2 = 0.7978845608f * (v + 0.044715f * v * v * v);
                    float e = __expf(2.0f * tt2);
                    float th = 1.0f - 2.0f / (e + 1.0f);
                    out[(size_t)rowg * N + colg] = (__bf16)(0.5f * v * (1.0f + th));
                }
            }
        }
    } else {
        __bf16* out = (__bf16*)outp + (size_t)blockIdx.y * BT * N;
#pragma unroll
        for (int i = 0; i < 4; i++) {
#pragma unroll
            for (int j = 0; j < 4; j++) {
                int colg = n0 + wn * 64 + j * 16 + lr;
#pragma unroll
                for (int r = 0; r < 4; r++) {
                    int rowg = m0 + wm * 64 + i * 16 + lrow + r;
                    out[(size_t)rowg * N + colg] = (__bf16)acc[i][j][r];
                }
            }
        }
    }
}

// ------------------------------------- final assembly (layer 12) -> d_out --
__global__ void final_reduce(const float* __restrict__ base,
                             const __bf16* __restrict__ part,
                             float* __restrict__ out)
{
    size_t i = ((size_t)blockIdx.x * 256 + threadIdx.x) * 4;
    f32x4 r = *(const f32x4*)(base + i);
#pragma unroll
    for (int z = 0; z < 4; z++) {
        bf16x4 p = *(const bf16x4*)(part + (size_t)z * BT * DIM + i);
#pragma unroll
        for (int c = 0; c < 4; c++) r[c] += (float)p[c];
    }
    *(f32x4*)(out + i) = r;
}

// ---------------------------------------------------------------- launch ---
extern "C" void kernel_launch(void* const* d_in, const int* in_sizes, int n_in,
                              void* d_out, int out_size, void* d_ws, size_t ws_size,
                              hipStream_t stream)
{
    const float* x   = (const float*)d_in[0];
    const float* q   = (const float*)d_in[1];
    const float* kng = (const float*)d_in[2];
    const float* knb = (const float*)d_in[3];
    const float* lng = (const float*)d_in[4];
    const float* lnb = (const float*)d_in[5];
    const float* W1  = (const float*)d_in[6];
    const float* b1  = (const float*)d_in[7];
    const float* W2  = (const float*)d_in[8];
    const float* b2  = (const float*)d_in[9];

    char* ws = (char*)d_ws;
    const size_t slot = (size_t)BT * DIM;            // 2M elements = 8 MB f32
    float*  hist  = (float*)(ws);                    // slots 1..12: 96 MB
    __bf16* ubuf  = (__bf16*)(ws + 100663296);       // 4 MB
    __bf16* hmid  = (__bf16*)(ws + 104857600);       // 16 MB
    __bf16* W1tb[2] = { (__bf16*)(ws + 121634816), (__bf16*)(ws + 130023424) };
    __bf16* W2tb[2] = { (__bf16*)(ws + 138412032), (__bf16*)(ws + 146800640) };
    __bf16* part  = (__bf16*)(ws + 155189248);       // 16 MB (end ~172 MB)

    wtrans_kernel<<<dim3(64, 16, 2), 256, 0, stream>>>(W1, W2, W1tb[0], W2tb[0]);

    for (int l = 0; l < NLAYER; l++) {
        int nl = l + 1;
        int ln = (l + 1 < NLAYER) ? l + 1 : l;
        float* hnext = hist + (size_t)l * slot;      // slot l+1
        attn_wt_kernel<<<dim3(2 * BT), 256, 0, stream>>>(
            x, hist, (l >= 1) ? part : (const __bf16*)nullptr,
            q + (size_t)l * DIM,
            kng + (size_t)l * DIM, knb + (size_t)l * DIM,
            lng + (size_t)l * DIM, lnb + (size_t)l * DIM,
            b2 + (size_t)l * DIM, hnext, ubuf, nl,
            W1 + (size_t)ln * DIM * EDIM, W2 + (size_t)ln * EDIM * DIM,
            W1tb[(l + 1) & 1], W2tb[(l + 1) & 1], (l + 1 < NLAYER) ? 1 : 0);
        gemm8<0><<<dim3(256, 1), 512, 0, stream>>>(
            ubuf, W1tb[l & 1], b1 + (size_t)l * EDIM, (void*)hmid, EDIM, DIM, DIM);
        gemm8<2><<<dim3(64, 4), 512, 0, stream>>>(
            hmid, W2tb[l & 1], nullptr, (void*)part, DIM, EDIM, EDIM);
    }

    final_reduce<<<dim3(BT * DIM / 1024), 256, 0, stream>>>(
        hist + (size_t)(NLAYER - 1) * slot, part, (float*)d_out);
}

// Round 9
// 897.018 us; speedup vs baseline: 1.3121x; 1.0214x over previous
//
#include <hip/hip_runtime.h>
#include <math.h>

#define BATCH 2
#define TSEQ 1024
#define DIM 1024
#define NLAYER 12
#define EDIM 4096
#define BT 2048
#define EPS_LN 1e-5f

typedef __attribute__((ext_vector_type(4))) float  f32x4;
typedef __attribute__((ext_vector_type(8))) __bf16 bf16x8;
typedef __attribute__((ext_vector_type(4))) __bf16 bf16x4;

__device__ __forceinline__ void gl_lds16(const void* gptr, void* lptr) {
    __builtin_amdgcn_global_load_lds(
        (const __attribute__((address_space(1))) void*)gptr,
        (__attribute__((address_space(3))) void*)lptr,
        16, 0, 0);
}

// ---- 64x64 f32->bf16 transpose tile, one 256-thread team ------------------
__device__ __forceinline__ void wtile256(float (*t)[65], const float* src,
                                         __bf16* dst, int R, int C,
                                         int rt, int ct, int tid)
{
    int lr = tid >> 2, cs = (tid & 3) << 4;
    const float* sp = src + (size_t)(rt * 64 + lr) * C + ct * 64 + cs;
#pragma unroll
    for (int s = 0; s < 4; s++) {
        f32x4 v = *(const f32x4*)(sp + s * 4);
        t[lr][cs + s * 4 + 0] = v[0];
        t[lr][cs + s * 4 + 1] = v[1];
        t[lr][cs + s * 4 + 2] = v[2];
        t[lr][cs + s * 4 + 3] = v[3];
    }
    __syncthreads();
    int oc = tid >> 2, rs = (tid & 3) << 4;
    bf16x8 o0, o1;
#pragma unroll
    for (int e = 0; e < 8; e++) o0[e] = (__bf16)t[rs + e][oc];
#pragma unroll
    for (int e = 0; e < 8; e++) o1[e] = (__bf16)t[rs + 8 + e][oc];
    __bf16* dp = dst + (size_t)(ct * 64 + oc) * R + rt * 64 + rs;
    *(bf16x8*)dp = o0;
    *(bf16x8*)(dp + 8) = o1;
}

// ----------------------------------------- standalone wtrans (layer 0) ----
__global__ __launch_bounds__(256) void wtrans_kernel(
    const float* __restrict__ W1, const float* __restrict__ W2,
    __bf16* __restrict__ W1t, __bf16* __restrict__ W2t)
{
    __shared__ float t[64][65];
    int z = blockIdx.z;
    if (z == 0) wtile256(t, W1, W1t, DIM, EDIM, blockIdx.y, blockIdx.x, threadIdx.x);
    else        wtile256(t, W2, W2t, EDIM, DIM, blockIdx.x, blockIdx.y, threadIdx.x);
}

// ---------------- fused: attn (blocks 0..2047) + wtrans (2048..4095) -------
// One block per bt row. Wave w owns history rows lp = w, w+4, w+8.
// Older rows (lp < nl-1) read from the bf16 mirror histbf (slot s at
// histbf + s*BT*DIM; slot 0 = bf16(x)). The newest row h_l is assembled:
// f32 baseprev (+ 4 bf16 split-K partials when part != NULL), then its
// bf16 image is written to mirror slot nl-1 (skipped for the last layer).
// Writes hnext = resid + b2 (f32) and u = LN(h) (bf16).
__global__ __launch_bounds__(256)
void attn_wt_kernel(const float* __restrict__ x,
                    const float* __restrict__ baseprev,
                    __bf16* __restrict__ histbf,
                    const __bf16* __restrict__ part,
                    const float* __restrict__ q,
                    const float* __restrict__ kng,
                    const float* __restrict__ knb,
                    const float* __restrict__ lng,
                    const float* __restrict__ lnb,
                    const float* __restrict__ b2,
                    float* __restrict__ hnext,
                    __bf16* __restrict__ u,
                    int nl,
                    const float* __restrict__ W1n,
                    const float* __restrict__ W2n,
                    __bf16* __restrict__ W1tn,
                    __bf16* __restrict__ W2tn,
                    int dowt)
{
    __shared__ char smem[49408];

    if (blockIdx.x >= BT) {
        if (!dowt) return;
        float (*t)[65] = (float(*)[65])smem;
        int tile = blockIdx.x - BT;
        if (tile < 1024) wtile256(t, W1n, W1tn, DIM, EDIM, tile >> 6, tile & 63, threadIdx.x);
        else { int t3 = tile - 1024; wtile256(t, W2n, W2tn, EDIM, DIM, t3 & 63, t3 >> 6, threadIdx.x); }
        return;
    }

    float (*V)[DIM] = (float(*)[DIM])smem;                    // [12][1024]
    float* sS  = (float*)(smem + 49152);
    float* sMu = sS + NLAYER;
    float* sRs = sMu + NLAYER;

    const int bt = blockIdx.x;
    const int tid = threadIdx.x, lane = tid & 63, w = tid >> 6;

    f32x4 gqv[4];
    float sg = 0.f, sb = 0.f;
#pragma unroll
    for (int i = 0; i < 4; i++) {
        int d = i * 256 + lane * 4;
        f32x4 g4 = *(const f32x4*)(kng + d);
        f32x4 q4 = *(const f32x4*)(q + d);
        f32x4 b4 = *(const f32x4*)(knb + d);
#pragma unroll
        for (int c = 0; c < 4; c++) {
            float gq = g4[c] * q4[c];
            gqv[i][c] = gq;
            sg += gq;
            sb += b4[c] * q4[c];
        }
    }
#pragma unroll
    for (int off = 32; off; off >>= 1) {
        sg += __shfl_xor(sg, off);
        sb += __shfl_xor(sb, off);
    }

    for (int lp = w; lp < nl; lp += 4) {
        f32x4 vv[4];
        if (lp == nl - 1) {
            // newest row: f32 base (+ partials), then publish bf16 mirror
            const float* vp = (nl == 1) ? (x + (size_t)bt * DIM)
                                        : (baseprev + (size_t)bt * DIM);
#pragma unroll
            for (int i = 0; i < 4; i++) vv[i] = *(const f32x4*)(vp + i * 256 + lane * 4);
            if (part) {
#pragma unroll
                for (int z = 0; z < 4; z++) {
                    const __bf16* pp = part + ((size_t)z * BT + bt) * DIM;
#pragma unroll
                    for (int i = 0; i < 4; i++) {
                        bf16x4 p4 = *(const bf16x4*)(pp + i * 256 + lane * 4);
#pragma unroll
                        for (int c = 0; c < 4; c++) vv[i][c] += (float)p4[c];
                    }
                }
            }
            if (nl < NLAYER) {
                __bf16* mp = histbf + ((size_t)lp * BT + bt) * DIM;
#pragma unroll
                for (int i = 0; i < 4; i++) {
                    bf16x4 m4;
#pragma unroll
                    for (int c = 0; c < 4; c++) m4[c] = (__bf16)vv[i][c];
                    *(bf16x4*)(mp + i * 256 + lane * 4) = m4;
                }
            }
        } else {
            const __bf16* mp = histbf + ((size_t)lp * BT + bt) * DIM;
#pragma unroll
            for (int i = 0; i < 4; i++) {
                bf16x4 m4 = *(const bf16x4*)(mp + i * 256 + lane * 4);
#pragma unroll
                for (int c = 0; c < 4; c++) vv[i][c] = (float)m4[c];
            }
        }

        float s1 = 0.f, s2 = 0.f, sq = 0.f;
#pragma unroll
        for (int i = 0; i < 4; i++) {
            *(f32x4*)(&V[lp][i * 256 + lane * 4]) = vv[i];
#pragma unroll
            for (int c = 0; c < 4; c++) {
                float xv = vv[i][c];
                s1 += xv; s2 += xv * xv; sq += xv * gqv[i][c];
            }
        }
#pragma unroll
        for (int off = 32; off; off >>= 1) {
            s1 += __shfl_xor(s1, off);
            s2 += __shfl_xor(s2, off);
            sq += __shfl_xor(sq, off);
        }
        if (lane == 0) {
            float mu = s1 * (1.0f / DIM);
            float var = s2 * (1.0f / DIM) - mu * mu;
            float rs = rsqrtf(var + EPS_LN);
            sMu[lp] = mu; sRs[lp] = rs;
            sS[lp] = (rs * (sq - mu * sg) + sb) * (1.0f / 32.0f);
        }
    }
    __syncthreads();

    float mx = -1e30f;
#pragma unroll
    for (int i = 0; i < NLAYER; i++) if (i < nl) mx = fmaxf(mx, sS[i]);
    float al[NLAYER];
    float ssum = 0.f;
#pragma unroll
    for (int i = 0; i < NLAYER; i++) {
        al[i] = (i < nl) ? __expf(sS[i] - mx) : 0.f;
        ssum += al[i];
    }
    float inv = 1.0f / ssum;

    const int d = tid * 4;
    f32x4 r; r[0] = 0.f; r[1] = 0.f; r[2] = 0.f; r[3] = 0.f;
#pragma unroll
    for (int i = 0; i < NLAYER; i++) {
        if (i < nl) {
            f32x4 v4 = *(const f32x4*)(&V[i][d]);
            float a = al[i] * inv;
            r[0] += a * v4[0]; r[1] += a * v4[1]; r[2] += a * v4[2]; r[3] += a * v4[3];
        }
    }
    f32x4 h4 = *(const f32x4*)(&V[nl - 1][d]);
    f32x4 b24 = *(const f32x4*)(b2 + d);
    f32x4 ro; ro[0] = r[0] + b24[0]; ro[1] = r[1] + b24[1];
    ro[2] = r[2] + b24[2]; ro[3] = r[3] + b24[3];
    *(f32x4*)(hnext + (size_t)bt * DIM + d) = ro;

    float mu = sMu[nl - 1], rs = sRs[nl - 1];
    f32x4 g4 = *(const f32x4*)(lng + d);
    f32x4 b4 = *(const f32x4*)(lnb + d);
    bf16x4 uo;
#pragma unroll
    for (int c = 0; c < 4; c++) uo[c] = (__bf16)((h4[c] - mu) * rs * g4[c] + b4[c]);
    *(bf16x4*)(u + (size_t)bt * DIM + d) = uo;
}

// ------------------------------------------------------------------ GEMM ---
// C = A(bf16 MxK) * Bt(bf16 NxK)^T.  128x256 tile, 8 waves (64x64 each),
// BK=64, triple-buffered LDS, prefetch depth 2, counted vmcnt(6), setprio.
// K per block fixed at 1024 (16 K-steps). IDENTITY m-fast tile mapping:
// consecutive blockIdx share an n-panel (chunked XCD assignment) while
// same-m0 blocks alias to one XCD under round-robin assignment.
// EPI==0: bf16 gelu(acc+bias) -> hmid. EPI==2: bf16 split-K partial slice.
#define STG 49152   // A 16KB + B 32KB per stage

template <int EPI>
__global__ __launch_bounds__(512, 1)
void gemm8(const __bf16* __restrict__ A, const __bf16* __restrict__ Bt,
           const float* __restrict__ bias, void* __restrict__ outp,
           int N, int As, int Bs)
{
    __shared__ char lds[3 * STG];          // 144 KB
    const int tid = threadIdx.x, lane = tid & 63, w = tid >> 6;
    const int wm = w >> 2, wn = w & 3;
    const int lr = lane & 15;
    const int hib = (lane >> 4) << 4;
    const int NT = 16;

    const int fid = blockIdx.x;
    const int m0 = (fid & 15) * 128;       // m fast, n slow (identity mapping)
    const int n0 = (fid >> 4) * 256;
    const int kbase = blockIdx.y * 1024;

    f32x4 acc[4][4];
#pragma unroll
    for (int i = 0; i < 4; i++)
#pragma unroll
        for (int j = 0; j < 4; j++) { acc[i][j][0]=0.f; acc[i][j][1]=0.f; acc[i][j][2]=0.f; acc[i][j][3]=0.f; }

    const int srow = tid >> 3;
    const int ksrc = ((tid & 7) << 4) ^ ((srow & 7) << 4);
    const char* Ac = (const char*)A;
    const char* Bc = (const char*)Bt;
    size_t aoff[2], boff[4];
#pragma unroll
    for (int c = 0; c < 2; c++)
        aoff[c] = ((size_t)(m0 + c * 64 + srow) * As + kbase) * 2 + ksrc;
#pragma unroll
    for (int c = 0; c < 4; c++)
        boff[c] = ((size_t)(n0 + c * 64 + srow) * Bs + kbase) * 2 + ksrc;

    char* abw = lds + w * 1024;
    char* bbw = lds + 16384 + w * 1024;

    auto STAGE = [&](int tt, int bi) {
        size_t kb = (size_t)tt * 128;
        char* ab = abw + bi * STG;
        char* bb = bbw + bi * STG;
#pragma unroll
        for (int c = 0; c < 2; c++) gl_lds16(Ac + aoff[c] + kb, ab + c * 8192);
#pragma unroll
        for (int c = 0; c < 4; c++) gl_lds16(Bc + boff[c] + kb, bb + c * 8192);
    };

    STAGE(0, 0);
    STAGE(1, 1);

    int sb = 0, st = 2;
#pragma unroll 1
    for (int t = 0; t < NT; ++t) {
        if (t < NT - 1) asm volatile("s_waitcnt vmcnt(6)" ::: "memory");
        else            asm volatile("s_waitcnt vmcnt(0)" ::: "memory");
        __builtin_amdgcn_s_barrier();
        __builtin_amdgcn_sched_barrier(0);

        if (t + 2 < NT) STAGE(t + 2, st);

        const char* base = lds + sb * STG;
        bf16x8 af[2][4], bfr[2][4];
#pragma unroll
        for (int kk = 0; kk < 2; kk++) {
#pragma unroll
            for (int i = 0; i < 4; i++) {
                int ra = wm * 64 + i * 16 + lr;
                af[kk][i] = *(const bf16x8*)(base + ra * 128 + ((kk * 64 + hib) ^ ((ra & 7) << 4)));
            }
#pragma unroll
            for (int j = 0; j < 4; j++) {
                int rb = wn * 64 + j * 16 + lr;
                bfr[kk][j] = *(const bf16x8*)(base + 16384 + rb * 128 + ((kk * 64 + hib) ^ ((rb & 7) << 4)));
            }
        }
        __builtin_amdgcn_s_setprio(1);
#pragma unroll
        for (int kk = 0; kk < 2; kk++)
#pragma unroll
            for (int i = 0; i < 4; i++)
#pragma unroll
                for (int j = 0; j < 4; j++)
                    acc[i][j] = __builtin_amdgcn_mfma_f32_16x16x32_bf16(af[kk][i], bfr[kk][j], acc[i][j], 0, 0, 0);
        __builtin_amdgcn_s_setprio(0);

        sb = (sb == 2) ? 0 : sb + 1;
        st = (st == 2) ? 0 : st + 1;
    }

    const int lrow = (lane >> 4) << 2;
    if (EPI == 0) {
        __bf16* out = (__bf16*)outp;
#pragma unroll
        for (int i = 0; i < 4; i++) {
#pragma unroll
            for (int j = 0; j < 4; j++) {
                int colg = n0 + wn * 64 + j * 16 + lr;
                float bc = bias[colg];
#pragma unroll
                for (int r = 0; r < 4; r++) {
                    int rowg = m0 + wm * 64 + i * 16 + lrow + r;
                    float v = acc[i][j][r] + bc;
                    float tt2 = 0.7978845608f * (v + 0.044715f * v * v * v);
                    float e = __expf(2.0f * tt2);
                    float th = 1.0f - 2.0f / (e + 1.0f);
                    out[(size_t)rowg * N + colg] = (__bf16)(0.5f * v * (1.0f + th));
                }
            }
        }
    } else {
        __bf16* out = (__bf16*)outp + (size_t)blockIdx.y * BT * N;
#pragma unroll
        for (int i = 0; i < 4; i++) {
#pragma unroll
            for (int j = 0; j < 4; j++) {
                int colg = n0 + wn * 64 + j * 16 + lr;
#pragma unroll
                for (int r = 0; r < 4; r++) {
                    int rowg = m0 + wm * 64 + i * 16 + lrow + r;
                    out[(size_t)rowg * N + colg] = (__bf16)acc[i][j][r];
                }
            }
        }
    }
}

// ------------------------------------- final assembly (layer 12) -> d_out --
__global__ void final_reduce(const float* __restrict__ base,
                             const __bf16* __restrict__ part,
                             float* __restrict__ out)
{
    size_t i = ((size_t)blockIdx.x * 256 + threadIdx.x) * 4;
    f32x4 r = *(const f32x4*)(base + i);
#pragma unroll
    for (int z = 0; z < 4; z++) {
        bf16x4 p = *(const bf16x4*)(part + (size_t)z * BT * DIM + i);
#pragma unroll
        for (int c = 0; c < 4; c++) r[c] += (float)p[c];
    }
    *(f32x4*)(out + i) = r;
}

// ---------------------------------------------------------------- launch ---
extern "C" void kernel_launch(void* const* d_in, const int* in_sizes, int n_in,
                              void* d_out, int out_size, void* d_ws, size_t ws_size,
                              hipStream_t stream)
{
    const float* x   = (const float*)d_in[0];
    const float* q   = (const float*)d_in[1];
    const float* kng = (const float*)d_in[2];
    const float* knb = (const float*)d_in[3];
    const float* lng = (const float*)d_in[4];
    const float* lnb = (const float*)d_in[5];
    const float* W1  = (const float*)d_in[6];
    const float* b1  = (const float*)d_in[7];
    const float* W2  = (const float*)d_in[8];
    const float* b2  = (const float*)d_in[9];

    char* ws = (char*)d_ws;
    const size_t MB = 1048576;
    float*  base2[2] = { (float*)(ws), (float*)(ws + 8 * MB) };   // f32 ping-pong
    __bf16* histbf = (__bf16*)(ws + 16 * MB);        // 12 bf16 slots: 48 MB
    __bf16* ubuf   = (__bf16*)(ws + 64 * MB);        // 4 MB
    __bf16* hmid   = (__bf16*)(ws + 68 * MB);        // 16 MB
    __bf16* W1tb[2] = { (__bf16*)(ws + 84 * MB), (__bf16*)(ws + 92 * MB) };
    __bf16* W2tb[2] = { (__bf16*)(ws + 100 * MB), (__bf16*)(ws + 108 * MB) };
    __bf16* part   = (__bf16*)(ws + 116 * MB);       // 16 MB (end 132 MB)

    wtrans_kernel<<<dim3(64, 16, 2), 256, 0, stream>>>(W1, W2, W1tb[0], W2tb[0]);

    for (int l = 0; l < NLAYER; l++) {
        int nl = l + 1;
        int ln = (l + 1 < NLAYER) ? l + 1 : l;
        float* hnext = base2[l & 1];
        const float* bprev = base2[(l + 1) & 1];
        attn_wt_kernel<<<dim3(2 * BT), 256, 0, stream>>>(
            x, bprev, histbf, (l >= 1) ? part : (const __bf16*)nullptr,
            q + (size_t)l * DIM,
            kng + (size_t)l * DIM, knb + (size_t)l * DIM,
            lng + (size_t)l * DIM, lnb + (size_t)l * DIM,
            b2 + (size_t)l * DIM, hnext, ubuf, nl,
            W1 + (size_t)ln * DIM * EDIM, W2 + (size_t)ln * EDIM * DIM,
            W1tb[(l + 1) & 1], W2tb[(l + 1) & 1], (l + 1 < NLAYER) ? 1 : 0);
        gemm8<0><<<dim3(256, 1), 512, 0, stream>>>(
            ubuf, W1tb[l & 1], b1 + (size_t)l * EDIM, (void*)hmid, EDIM, DIM, DIM);
        gemm8<2><<<dim3(64, 4), 512, 0, stream>>>(
            hmid, W2tb[l & 1], nullptr, (void*)part, DIM, EDIM, EDIM);
    }

    final_reduce<<<dim3(BT * DIM / 1024), 256, 0, stream>>>(
        base2[1], part, (float*)d_out);
}